// Round 1
// baseline (819.199 us; speedup 1.0000x reference)
//
#include <hip/hip_runtime.h>
#include <hip/hip_bf16.h>
#include <math.h>

typedef __attribute__((ext_vector_type(8))) short short8;   // 8 x bf16 (4 VGPRs)
typedef __attribute__((ext_vector_type(4))) float f32x4;    // MFMA C/D frag

#define NN    21
#define DD    256
#define GH    512
#define NE    40
#define BT    6               // batches per workgroup
#define MROWS (BT * NN)       // 126 real rows
#define MPAD  128             // padded M tile
#define XSTR  264             // bf16 row stride (256 + 8): 2-way-max LDS banks on b128 reads
#define UVSTR 68              // fp32 row stride (64 + 4)
#define NTHR  512

__device__ __forceinline__ f32x4 mfma16(short8 a, short8 b, f32x4 c) {
    return __builtin_amdgcn_mfma_f32_16x16x32_bf16(a, b, c, 0, 0, 0);
}

// ---------------------------------------------------------------------------
// Prep: transpose weights to bf16 [n][k] layouts so MFMA B-frag LDS staging is
// coalesced. WvT[f][d] = Wv[d][f]; WtT[h][c] = W1[c][h] (c<256);
// WbT[h][c] = W1[256+c][h].
// ---------------------------------------------------------------------------
__global__ void prep_weights(const float* __restrict__ Wv, const float* __restrict__ W1,
                             __hip_bfloat16* __restrict__ WvT,
                             __hip_bfloat16* __restrict__ WtT,
                             __hip_bfloat16* __restrict__ WbT) {
    __shared__ float tile[64][65];
    int bi = blockIdx.x;
    const float* src;
    int ld, tc, th;
    bool isW1 = bi < 64;
    if (isW1) { src = W1; ld = 512; tc = (bi & 7) * 64; th = (bi >> 3) * 64; }
    else      { int b = bi - 64; src = Wv; ld = 256; tc = (b & 3) * 64; th = (b >> 2) * 64; }
    for (int i = 0; i < 16; ++i) {
        int e = threadIdx.x + 256 * i;
        int r = e >> 6, cc = e & 63;
        tile[r][cc] = src[(size_t)(tc + r) * ld + th + cc];
    }
    __syncthreads();
    for (int i = 0; i < 16; ++i) {
        int e  = threadIdx.x + 256 * i;
        int r2 = e >> 6, cc2 = e & 63;
        float v = tile[cc2][r2];
        int hh = th + r2, c = tc + cc2;
        if (isW1) {
            if (c < 256) WtT[hh * 256 + c]         = __float2bfloat16(v);
            else         WbT[hh * 256 + (c - 256)] = __float2bfloat16(v);
        } else {
            WvT[hh * 256 + c] = __float2bfloat16(v);
        }
    }
}

// ---------------------------------------------------------------------------
// Fused: LN -> (U,V chunks + per-edge gate dot) -> gates -> G -> Val chunks ->
// out = h + G @ Val.  One WG owns BT=6 batches end-to-end; no global scratch
// except prepped weights.
// ---------------------------------------------------------------------------
__launch_bounds__(NTHR)
__global__ void fused_kernel(const float* __restrict__ hin,
                             const int* __restrict__ srci, const int* __restrict__ dsti,
                             const float* __restrict__ lnw, const float* __restrict__ lnb,
                             const float* __restrict__ bv,  const float* __restrict__ b1,
                             const float* __restrict__ W2,  const float* __restrict__ b2,
                             const __hip_bfloat16* __restrict__ WvT,
                             const __hip_bfloat16* __restrict__ WtT,
                             const __hip_bfloat16* __restrict__ WbT,
                             float* __restrict__ out, int Btotal) {
    __shared__ __hip_bfloat16 xs[MPAD][XSTR];      // LN'd x tile (A matrix), 67.6 KB
    __shared__ __hip_bfloat16 wst[64][XSTR];       // staged B chunk (64 n-rows), 33.8 KB
    __shared__ float uv[MPAD][UVSTR];              // U|V (or Val) chunk, 34.8 KB
    __shared__ float gpart[2][256];
    __shared__ float G[BT][NN][NN];
    __shared__ float b1s[GH], w2s[GH], bvs[DD];
    __shared__ int   srcs[NE], dsts[NE];

    const int tid  = threadIdx.x;
    const int lane = tid & 63;
    const int w    = tid >> 6;          // wave 0..7
    const int b0   = blockIdx.x * BT;   // first global batch of this WG

    if (tid < NE) { srcs[tid] = srci[tid]; dsts[tid] = dsti[tid]; }
    if (tid < GH) { b1s[tid] = b1[tid]; w2s[tid] = W2[tid]; }
    if (tid < DD) { bvs[tid] = bv[tid]; }

    // ---- Phase 1: LayerNorm -> xs (bf16) ----
    {
        float4 wgt = ((const float4*)lnw)[lane];
        float4 bta = ((const float4*)lnb)[lane];
        for (int r = w; r < MPAD; r += 8) {
            int b_loc = r / NN;
            int node  = r - b_loc * NN;
            bool valid = (r < MROWS) && (b0 + b_loc < Btotal);
            float4 h4 = {0.f, 0.f, 0.f, 0.f};
            if (valid)
                h4 = ((const float4*)(hin + ((size_t)(b0 + b_loc) * NN + node) * DD))[lane];
            float s  = h4.x + h4.y + h4.z + h4.w;
            float ss = h4.x*h4.x + h4.y*h4.y + h4.z*h4.z + h4.w*h4.w;
            for (int off = 32; off; off >>= 1) {
                s  += __shfl_xor(s,  off);
                ss += __shfl_xor(ss, off);
            }
            float mu   = s * (1.0f / 256.0f);
            float var  = ss * (1.0f / 256.0f) - mu * mu;
            float rstd = rsqrtf(var + 1e-5f);
            __hip_bfloat16* xr = &xs[r][lane * 4];
            if (valid) {
                xr[0] = __float2bfloat16((h4.x - mu) * rstd * wgt.x + bta.x);
                xr[1] = __float2bfloat16((h4.y - mu) * rstd * wgt.y + bta.y);
                xr[2] = __float2bfloat16((h4.z - mu) * rstd * wgt.z + bta.z);
                xr[3] = __float2bfloat16((h4.w - mu) * rstd * wgt.w + bta.w);
            } else {
                __hip_bfloat16 z = __float2bfloat16(0.0f);
                xr[0] = z; xr[1] = z; xr[2] = z; xr[3] = z;
            }
        }
    }
    __syncthreads();

    // wave tile: 4x2 grid over (M=128, N=64)
    const int mq  = w & 3;        // m block: rows 32*mq..+32
    const int nh  = w >> 2;       // n half: cols 32*nh..+32
    const int l15 = lane & 15;
    const int lq  = lane >> 4;

    // gate-dot ownership: pair p = gidx (<240), j-half = ghalf
    const int gidx  = tid & 255;
    const int ghalf = tid >> 8;
    const int pb = gidx / NE;
    const int pe = gidx - pb * NE;
    float gaccr = 0.0f;

    // ---- Phase 2: 16 chunks of U(top)/V(bot), 32 gh-cols each ----
    for (int c = 0; c < 16; ++c) {
        {   // stage 64 n-rows x 256 k (bf16) -> wst
            const __hip_bfloat16* baset = WtT + (size_t)c * 32 * 256;
            const __hip_bfloat16* baseb = WbT + (size_t)c * 32 * 256;
            #pragma unroll
            for (int i = 0; i < 4; ++i) {
                int v   = tid + NTHR * i;      // 0..2047
                int row = v >> 5;              // 0..63
                int kv  = (v & 31) * 8;
                const __hip_bfloat16* sp =
                    (row < 32) ? (baset + row * 256 + kv) : (baseb + (row - 32) * 256 + kv);
                *(float4*)&wst[row][kv] = *(const float4*)sp;
            }
        }
        __syncthreads();

        f32x4 acc[2][2];
        #pragma unroll
        for (int mt = 0; mt < 2; ++mt)
            #pragma unroll
            for (int nt = 0; nt < 2; ++nt)
                acc[mt][nt] = (f32x4){0.f, 0.f, 0.f, 0.f};
        #pragma unroll
        for (int ki = 0; ki < 8; ++ki) {
            int k0 = ki * 32 + lq * 8;
            short8 a0 = *(const short8*)&xs[32 * mq + l15][k0];
            short8 a1 = *(const short8*)&xs[32 * mq + 16 + l15][k0];
            short8 bb0 = *(const short8*)&wst[32 * nh + l15][k0];
            short8 bb1 = *(const short8*)&wst[32 * nh + 16 + l15][k0];
            acc[0][0] = mfma16(a0, bb0, acc[0][0]);
            acc[0][1] = mfma16(a0, bb1, acc[0][1]);
            acc[1][0] = mfma16(a1, bb0, acc[1][0]);
            acc[1][1] = mfma16(a1, bb1, acc[1][1]);
        }
        #pragma unroll
        for (int mt = 0; mt < 2; ++mt)
            #pragma unroll
            for (int nt = 0; nt < 2; ++nt)
                #pragma unroll
                for (int r = 0; r < 4; ++r)
                    uv[32 * mq + 16 * mt + 4 * lq + r][32 * nh + 16 * nt + l15] = acc[mt][nt][r];
        __syncthreads();

        // per-edge gate partial: gelu(U[src]+V[dst]+b1) . W2
        if (gidx < BT * NE) {
            int rs = pb * NN + srcs[pe];
            int rd = pb * NN + dsts[pe];
            int jb = ghalf * 16;
            #pragma unroll
            for (int jj = 0; jj < 16; ++jj) {
                int j = jb + jj;
                float z  = uv[rs][j] + uv[rd][32 + j] + b1s[c * 32 + j];
                float ge = 0.5f * z * (1.0f + erff(z * 0.70710678118f));
                gaccr += ge * w2s[c * 32 + j];
            }
        }
        __syncthreads();
    }

    // ---- Phase 3: gates -> G (21x21 incidence per batch) ----
    gpart[ghalf][gidx] = gaccr;
    __syncthreads();
    for (int i = tid; i < BT * NN * NN; i += NTHR) ((float*)G)[i] = 0.0f;
    __syncthreads();
    if (ghalf == 0 && gidx < BT * NE) {
        float tot  = gpart[0][gidx] + gpart[1][gidx] + b2[0];
        float gate = 1.0f / (1.0f + __expf(-tot));
        atomicAdd(&G[pb][dsts[pe]][srcs[pe]], gate);
    }
    __syncthreads();

    // ---- Phase 4: Val chunks (64 f-cols each) + agg + write out ----
    for (int vc = 0; vc < 4; ++vc) {
        #pragma unroll
        for (int i = 0; i < 4; ++i) {
            int v   = tid + NTHR * i;
            int row = v >> 5;
            int kv  = (v & 31) * 8;
            *(float4*)&wst[row][kv] = *(const float4*)(WvT + (size_t)(vc * 64 + row) * 256 + kv);
        }
        __syncthreads();

        f32x4 acc[2][2];
        #pragma unroll
        for (int mt = 0; mt < 2; ++mt)
            #pragma unroll
            for (int nt = 0; nt < 2; ++nt)
                acc[mt][nt] = (f32x4){0.f, 0.f, 0.f, 0.f};
        #pragma unroll
        for (int ki = 0; ki < 8; ++ki) {
            int k0 = ki * 32 + lq * 8;
            short8 a0 = *(const short8*)&xs[32 * mq + l15][k0];
            short8 a1 = *(const short8*)&xs[32 * mq + 16 + l15][k0];
            short8 bb0 = *(const short8*)&wst[32 * nh + l15][k0];
            short8 bb1 = *(const short8*)&wst[32 * nh + 16 + l15][k0];
            acc[0][0] = mfma16(a0, bb0, acc[0][0]);
            acc[0][1] = mfma16(a0, bb1, acc[0][1]);
            acc[1][0] = mfma16(a1, bb0, acc[1][0]);
            acc[1][1] = mfma16(a1, bb1, acc[1][1]);
        }
        #pragma unroll
        for (int mt = 0; mt < 2; ++mt)
            #pragma unroll
            for (int nt = 0; nt < 2; ++nt)
                #pragma unroll
                for (int r = 0; r < 4; ++r) {
                    int col = 32 * nh + 16 * nt + l15;
                    uv[32 * mq + 16 * mt + 4 * lq + r][col] = acc[mt][nt][r] + bvs[vc * 64 + col];
                }
        __syncthreads();

        // out[b,node, vc*64 + 0..63] = h + sum_sn G[b][node][sn] * Val[sn]
        #pragma unroll
        for (int qi = 0; qi < 4; ++qi) {
            int q = tid + NTHR * qi;
            if (q < MROWS * 16) {
                int row   = q >> 4;
                int cq    = q & 15;
                int b_loc = row / NN;
                int node  = row - b_loc * NN;
                if (b0 + b_loc < Btotal) {
                    size_t gaddr = ((size_t)(b0 + b_loc) * NN + node) * DD + vc * 64 + cq * 4;
                    float4 hv = *(const float4*)(hin + gaddr);
                    float a0 = hv.x, a1 = hv.y, a2 = hv.z, a3 = hv.w;
                    #pragma unroll
                    for (int sn = 0; sn < NN; ++sn) {
                        float gv = G[b_loc][node][sn];
                        const float* vp = &uv[b_loc * NN + sn][cq * 4];
                        a0 += gv * vp[0]; a1 += gv * vp[1];
                        a2 += gv * vp[2]; a3 += gv * vp[3];
                    }
                    float4 o = {a0, a1, a2, a3};
                    *(float4*)(out + gaddr) = o;
                }
            }
        }
        __syncthreads();
    }
}

extern "C" void kernel_launch(void* const* d_in, const int* in_sizes, int n_in,
                              void* d_out, int out_size, void* d_ws, size_t ws_size,
                              hipStream_t stream) {
    const float* h   = (const float*)d_in[0];
    const int*  srci = (const int*)d_in[1];
    const int*  dsti = (const int*)d_in[2];
    const float* lnw = (const float*)d_in[3];
    const float* lnb = (const float*)d_in[4];
    const float* Wv  = (const float*)d_in[5];
    const float* bv  = (const float*)d_in[6];
    const float* W1  = (const float*)d_in[7];
    const float* b1  = (const float*)d_in[8];
    const float* W2  = (const float*)d_in[9];
    const float* b2  = (const float*)d_in[10];
    float* out = (float*)d_out;

    __hip_bfloat16* WvT = (__hip_bfloat16*)d_ws;       // 256*256
    __hip_bfloat16* WtT = WvT + 256 * 256;             // 512*256
    __hip_bfloat16* WbT = WtT + 512 * 256;             // 512*256

    int Btotal = in_sizes[0] / (NN * DD);
    prep_weights<<<80, 256, 0, stream>>>(Wv, W1, WvT, WtT, WbT);
    int grid = (Btotal + BT - 1) / BT;
    fused_kernel<<<grid, NTHR, 0, stream>>>(h, srci, dsti, lnw, lnb, bv, b1, W2, b2,
                                            WvT, WtT, WbT, out, Btotal);
}

// Round 2
// 599.494 us; speedup vs baseline: 1.3665x; 1.3665x over previous
//
#include <hip/hip_runtime.h>
#include <hip/hip_bf16.h>
#include <math.h>

typedef __attribute__((ext_vector_type(8))) short short8;   // 8 x bf16 (4 VGPRs)
typedef __attribute__((ext_vector_type(4))) float f32x4;    // MFMA C/D frag

#define NN    21
#define DD    256
#define GH    512
#define NE    40
#define BT    3               // batches per workgroup
#define MROWS (BT * NN)       // 63 real rows
#define MPAD  64              // padded M tile
#define NTHR  256
#define UVSTR 36              // fp32 row stride for uv (32 + 4)

__device__ __forceinline__ f32x4 mfma16(short8 a, short8 b, f32x4 c) {
    return __builtin_amdgcn_mfma_f32_16x16x32_bf16(a, b, c, 0, 0, 0);
}

// ---------------------------------------------------------------------------
// Prep: transpose weights to bf16 [n][k] layouts. WvT[f][d] = Wv[d][f];
// WtT[h][c] = W1[c][h] (c<256); WbT[h][c] = W1[256+c][h].
// ---------------------------------------------------------------------------
__global__ void prep_weights(const float* __restrict__ Wv, const float* __restrict__ W1,
                             __hip_bfloat16* __restrict__ WvT,
                             __hip_bfloat16* __restrict__ WtT,
                             __hip_bfloat16* __restrict__ WbT) {
    __shared__ float tile[64][65];
    int bi = blockIdx.x;
    const float* src;
    int ld, tc, th;
    bool isW1 = bi < 64;
    if (isW1) { src = W1; ld = 512; tc = (bi & 7) * 64; th = (bi >> 3) * 64; }
    else      { int b = bi - 64; src = Wv; ld = 256; tc = (b & 3) * 64; th = (b >> 2) * 64; }
    for (int i = 0; i < 16; ++i) {
        int e = threadIdx.x + 256 * i;
        int r = e >> 6, cc = e & 63;
        tile[r][cc] = src[(size_t)(tc + r) * ld + th + cc];
    }
    __syncthreads();
    for (int i = 0; i < 16; ++i) {
        int e  = threadIdx.x + 256 * i;
        int r2 = e >> 6, cc2 = e & 63;
        float v = tile[cc2][r2];
        int hh = th + r2, c = tc + cc2;
        if (isW1) {
            if (c < 256) WtT[hh * 256 + c]         = __float2bfloat16(v);
            else         WbT[hh * 256 + (c - 256)] = __float2bfloat16(v);
        } else {
            WvT[hh * 256 + c] = __float2bfloat16(v);
        }
    }
}

// ---------------------------------------------------------------------------
// Fused kernel. 1 WG = 3 batches (63 rows, pad 64), 256 threads / 4 waves.
// A-fragments live in registers; xs LDS region is reused as wst+uv.
// XOR swizzle: content 16B-granule g of row r stored at phys granule g^(r&7).
// ---------------------------------------------------------------------------
__launch_bounds__(NTHR, 3)
__global__ void fused_kernel(const float* __restrict__ hin,
                             const int* __restrict__ srci, const int* __restrict__ dsti,
                             const float* __restrict__ lnw, const float* __restrict__ lnb,
                             const float* __restrict__ bv,  const float* __restrict__ b1,
                             const float* __restrict__ W2,  const float* __restrict__ b2,
                             const __hip_bfloat16* __restrict__ WvT,
                             const __hip_bfloat16* __restrict__ WtT,
                             const __hip_bfloat16* __restrict__ WbT,
                             float* __restrict__ out, int Btotal) {
    // phase A: xs[64 rows][512 B] swizzled bf16 (32 KB)
    // phase B: wst = smem[0..16384) (32 rows x 512 B swizzled bf16),
    //          uv  = (float*)(smem+16384), [64][UVSTR] (9.2 KB)
    __shared__ __align__(16) char smem[32768];
    __shared__ float b1s[GH], w2s[GH], bvs[DD];
    __shared__ float gates[BT * NE];
    __shared__ int   srcs[NE], dsts[NE];
    __shared__ int   csr_off[NN + 1], csr_cur[NN], csr_eid[NE];

    const int tid  = threadIdx.x;
    const int lane = tid & 63;
    const int w    = tid >> 6;          // wave 0..3
    const int b0   = blockIdx.x * BT;

    if (tid < NE) { srcs[tid] = srci[tid]; dsts[tid] = dsti[tid]; }
    b1s[tid] = b1[tid];  b1s[tid + 256] = b1[tid + 256];
    w2s[tid] = W2[tid];  w2s[tid + 256] = W2[tid + 256];
    bvs[tid] = bv[tid];
    if (tid <= NN) csr_off[tid] = 0;
    int myd = (tid < NE) ? dsti[tid] : 0;
    __syncthreads();
    if (tid < NE) atomicAdd(&csr_off[myd + 1], 1);

    // ---- Phase 1: LayerNorm -> xs (bf16, swizzled) ----
    {
        float4 wgt = ((const float4*)lnw)[lane];
        float4 bta = ((const float4*)lnb)[lane];
        for (int r = w; r < MPAD; r += 4) {
            int b_loc = r / NN;
            int node  = r - b_loc * NN;
            bool valid = (r < MROWS) && (b0 + b_loc < Btotal);
            float4 h4 = {0.f, 0.f, 0.f, 0.f};
            if (valid)
                h4 = *(const float4*)(hin + ((size_t)(b0 + b_loc) * NN + node) * DD + lane * 4);
            float s  = h4.x + h4.y + h4.z + h4.w;
            float ss = h4.x*h4.x + h4.y*h4.y + h4.z*h4.z + h4.w*h4.w;
            for (int off = 32; off; off >>= 1) {
                s  += __shfl_xor(s,  off);
                ss += __shfl_xor(ss, off);
            }
            float mu   = s * (1.0f / 256.0f);
            float rstd = rsqrtf(ss * (1.0f / 256.0f) - mu * mu + 1e-5f);
            __align__(8) __hip_bfloat16 t[4];
            if (valid) {
                t[0] = __float2bfloat16((h4.x - mu) * rstd * wgt.x + bta.x);
                t[1] = __float2bfloat16((h4.y - mu) * rstd * wgt.y + bta.y);
                t[2] = __float2bfloat16((h4.z - mu) * rstd * wgt.z + bta.z);
                t[3] = __float2bfloat16((h4.w - mu) * rstd * wgt.w + bta.w);
            } else {
                __hip_bfloat16 z = __float2bfloat16(0.0f);
                t[0] = z; t[1] = z; t[2] = z; t[3] = z;
            }
            char* dst = smem + r * 512 + ((((lane >> 1) ^ (r & 7)) << 4) | ((lane & 1) << 3));
            *(ushort4*)dst = *(ushort4*)&t[0];
        }
    }
    __syncthreads();

    // ---- CSR build (thread 0, overlapped with A-frag loads) ----
    if (tid == 0) {
        for (int n = 0; n < NN; ++n) csr_off[n + 1] += csr_off[n];
        for (int n = 0; n < NN; ++n) csr_cur[n] = csr_off[n];
        for (int e = 0; e < NE; ++e) { int d = dsts[e]; csr_eid[csr_cur[d]++] = e; }
    }

    // ---- A-fragments -> registers (wave grid: mq = m-half, nsel = U/V) ----
    const int mq   = w & 1;
    const int nsel = w >> 1;
    const int l15  = lane & 15;
    const int lq   = lane >> 4;
    short8 afr[2][8];
    #pragma unroll
    for (int mt = 0; mt < 2; ++mt) {
        int r = 32 * mq + 16 * mt + l15;
        const char* rowp = smem + r * 512;
        int swz = r & 7;
        #pragma unroll
        for (int ki = 0; ki < 8; ++ki)
            afr[mt][ki] = *(const short8*)(rowp + ((((ki << 2) + lq) ^ swz) << 4));
    }
    __syncthreads();   // xs dead beyond this point; smem becomes wst, +16K uv

    float* uvp = (float*)(smem + 16384);

    // gate ownership: pair p = tid>>1 (120 pairs), j-half = tid&1
    const bool gactive = tid < 2 * BT * NE;   // 240
    int rs = 0, rd = 0;
    if (gactive) {
        int p  = tid >> 1;
        int pb = p / NE, pe = p - pb * NE;
        rs = pb * NN + srcs[pe];
        rd = pb * NN + dsts[pe];
    }
    const int jh = tid & 1;

    // stage U/V chunk 0: wst rows 0-15 <- WtT rows 0..15, rows 16-31 <- WbT
    #pragma unroll
    for (int i = 0; i < 4; ++i) {
        int v = tid + NTHR * i;
        int row = v >> 5, pg = v & 31;
        int cg = pg ^ (row & 7);
        const __hip_bfloat16* sp = (row < 16)
            ? (WtT + (size_t)row * 256 + cg * 8)
            : (WbT + (size_t)(row - 16) * 256 + cg * 8);
        *(float4*)(smem + row * 512 + pg * 16) = *(const float4*)sp;
    }
    __syncthreads();

    // ---- Phase 2: 32 chunks of 16 gh-cols (U and V simultaneously) ----
    float gacc = 0.0f;
    const int   brow_r = 16 * nsel + l15;
    const char* browp  = smem + brow_r * 512;
    const int   bswz   = l15 & 7;
    for (int c = 0; c < 32; ++c) {
        f32x4 acc0 = {0.f,0.f,0.f,0.f}, acc1 = {0.f,0.f,0.f,0.f};
        #pragma unroll
        for (int ki = 0; ki < 8; ++ki) {
            short8 bf = *(const short8*)(browp + ((((ki << 2) + lq) ^ bswz) << 4));
            acc0 = mfma16(afr[0][ki], bf, acc0);
            acc1 = mfma16(afr[1][ki], bf, acc1);
        }
        #pragma unroll
        for (int r = 0; r < 4; ++r) {
            int col = 16 * nsel + l15;
            uvp[(32 * mq +      4 * lq + r) * UVSTR + col] = acc0[r];
            uvp[(32 * mq + 16 + 4 * lq + r) * UVSTR + col] = acc1[r];
        }
        __syncthreads();
        // gate partials (reads uv) overlapped with staging chunk c+1 (writes wst)
        if (gactive) {
            const float* up  = uvp + rs * UVSTR + jh * 8;
            const float* vp  = uvp + rd * UVSTR + 16 + jh * 8;
            const float* b1p = b1s + c * 16 + jh * 8;
            const float* w2p = w2s + c * 16 + jh * 8;
            #pragma unroll
            for (int jj = 0; jj < 8; ++jj) {
                float z = up[jj] + vp[jj] + b1p[jj];
                // gelu(z) ~= z * sigmoid(1.5957692*(z + 0.044715 z^3))
                float y = 1.5957691216f * (z + 0.044715f * z * z * z);
                float s = 1.0f / (1.0f + __expf(-y));
                gacc += z * s * w2p[jj];
            }
        }
        if (c + 1 < 32) {
            int cb = c + 1;
            #pragma unroll
            for (int i = 0; i < 4; ++i) {
                int v = tid + NTHR * i;
                int row = v >> 5, pg = v & 31;
                int cg = pg ^ (row & 7);
                const __hip_bfloat16* sp = (row < 16)
                    ? (WtT + (size_t)(cb * 16 + row) * 256 + cg * 8)
                    : (WbT + (size_t)(cb * 16 + row - 16) * 256 + cg * 8);
                *(float4*)(smem + row * 512 + pg * 16) = *(const float4*)sp;
            }
        }
        __syncthreads();
    }

    // ---- Phase 3: finalize gates (shuffle-pair reduce) + stage Val chunk 0 ----
    if (gactive) {
        float other = __shfl_xor(gacc, 1);
        if (jh == 0) {
            float tot = gacc + other + b2[0];
            gates[tid >> 1] = 1.0f / (1.0f + __expf(-tot));
        }
    }
    #pragma unroll
    for (int i = 0; i < 4; ++i) {
        int v = tid + NTHR * i;
        int row = v >> 5, pg = v & 31;
        int cg = pg ^ (row & 7);
        *(float4*)(smem + row * 512 + pg * 16) =
            *(const float4*)(WvT + (size_t)row * 256 + cg * 8);
    }
    __syncthreads();

    // ---- Phase 4: 8 Val chunks (32 f-cols) -> CSR aggregation -> out ----
    for (int vc = 0; vc < 8; ++vc) {
        f32x4 acc0 = {0.f,0.f,0.f,0.f}, acc1 = {0.f,0.f,0.f,0.f};
        #pragma unroll
        for (int ki = 0; ki < 8; ++ki) {
            short8 bf = *(const short8*)(browp + ((((ki << 2) + lq) ^ bswz) << 4));
            acc0 = mfma16(afr[0][ki], bf, acc0);
            acc1 = mfma16(afr[1][ki], bf, acc1);
        }
        #pragma unroll
        for (int r = 0; r < 4; ++r) {
            int col = 16 * nsel + l15;
            float bvv = bvs[vc * 32 + col];
            uvp[(32 * mq +      4 * lq + r) * UVSTR + col] = acc0[r] + bvv;
            uvp[(32 * mq + 16 + 4 * lq + r) * UVSTR + col] = acc1[r] + bvv;
        }
        __syncthreads();
        // aggregation (reads uv/gates/csr) overlapped with staging vc+1 (writes wst)
        for (int q = tid; q < MROWS * 8; q += NTHR) {
            int row = q >> 3, g = q & 7;
            int b_loc = row / NN;
            int node  = row - b_loc * NN;
            if (b0 + b_loc < Btotal) {
                size_t ga = ((size_t)(b0 + b_loc) * NN + node) * DD + vc * 32 + g * 4;
                float4 hv = *(const float4*)(hin + ga);
                float a0 = hv.x, a1 = hv.y, a2 = hv.z, a3 = hv.w;
                int e1 = csr_off[node + 1];
                for (int ii = csr_off[node]; ii < e1; ++ii) {
                    int e  = csr_eid[ii];
                    float gv = gates[b_loc * NE + e];
                    const float* vp = uvp + (b_loc * NN + srcs[e]) * UVSTR + g * 4;
                    a0 += gv * vp[0]; a1 += gv * vp[1];
                    a2 += gv * vp[2]; a3 += gv * vp[3];
                }
                float4 o = {a0, a1, a2, a3};
                *(float4*)(out + ga) = o;
            }
        }
        if (vc + 1 < 8) {
            int vb = vc + 1;
            #pragma unroll
            for (int i = 0; i < 4; ++i) {
                int v = tid + NTHR * i;
                int row = v >> 5, pg = v & 31;
                int cg = pg ^ (row & 7);
                *(float4*)(smem + row * 512 + pg * 16) =
                    *(const float4*)(WvT + (size_t)(vb * 32 + row) * 256 + cg * 8);
            }
        }
        __syncthreads();
    }
}

extern "C" void kernel_launch(void* const* d_in, const int* in_sizes, int n_in,
                              void* d_out, int out_size, void* d_ws, size_t ws_size,
                              hipStream_t stream) {
    const float* h   = (const float*)d_in[0];
    const int*  srci = (const int*)d_in[1];
    const int*  dsti = (const int*)d_in[2];
    const float* lnw = (const float*)d_in[3];
    const float* lnb = (const float*)d_in[4];
    const float* Wv  = (const float*)d_in[5];
    const float* bv  = (const float*)d_in[6];
    const float* W1  = (const float*)d_in[7];
    const float* b1  = (const float*)d_in[8];
    const float* W2  = (const float*)d_in[9];
    const float* b2  = (const float*)d_in[10];
    float* out = (float*)d_out;

    __hip_bfloat16* WvT = (__hip_bfloat16*)d_ws;       // 256*256
    __hip_bfloat16* WtT = WvT + 256 * 256;             // 512*256
    __hip_bfloat16* WbT = WtT + 512 * 256;             // 512*256

    int Btotal = in_sizes[0] / (NN * DD);
    prep_weights<<<80, 256, 0, stream>>>(Wv, W1, WvT, WtT, WbT);
    int grid = (Btotal + BT - 1) / BT;
    fused_kernel<<<grid, NTHR, 0, stream>>>(h, srci, dsti, lnw, lnb, bv, b1, W2, b2,
                                            WvT, WtT, WbT, out, Btotal);
}